// Round 2
// baseline (590.602 us; speedup 1.0000x reference)
//
#include <hip/hip_runtime.h>
#include <stdint.h>

#define DEV __device__ __forceinline__

typedef __attribute__((__ext_vector_type__(8))) short short8;
typedef __attribute__((__ext_vector_type__(4))) float f32x4;
typedef __attribute__((__ext_vector_type__(4))) unsigned short ushort4_t;

// ---------- helpers ----------
DEV unsigned short f2bf(float f) {
  union { float f; unsigned u; } x; x.f = f;
  unsigned u = x.u;
  unsigned r = (u + 0x7FFFu + ((u >> 16) & 1u)) >> 16;  // RNE
  return (unsigned short)r;
}

DEV void gload_lds16(const void* g, void* l) {
  __builtin_amdgcn_global_load_lds(
      (const __attribute__((address_space(1))) unsigned int*)g,
      (__attribute__((address_space(3))) unsigned int*)l,
      16, 0, 0);
}

DEV short8 ld_g8(const unsigned short* p) { return *(const short8*)p; }
DEV short8 ld_s8(const unsigned short* p) { return *(const short8*)p; }

// ---------- mask dtype detection ----------
// fmt: 0 = packed bool bytes, 1 = int32 0/1, 2 = float32 0.0/1.0
__global__ void detect_mask_fmt(const unsigned int* __restrict__ mask, int* __restrict__ flag) {
  if (threadIdx.x == 0 && blockIdx.x == 0) {
    int fmt = 1;
    for (int i = 0; i < 256; ++i) {
      unsigned u = mask[i];
      if (u == 0x3F800000u) { fmt = 2; break; }
      if ((u & 0xFFFFFF00u) != 0u) { fmt = 0; break; }
    }
    *flag = fmt;
  }
}

// ---------- fp32 -> bf16 convert ----------
__global__ void cvt_kernel(const float* __restrict__ in, unsigned short* __restrict__ out, int n4) {
  int i = blockIdx.x * blockDim.x + threadIdx.x;
  if (i < n4) {
    float4 v = ((const float4*)in)[i];
    ushort4_t r;
    r.x = f2bf(v.x); r.y = f2bf(v.y); r.z = f2bf(v.z); r.w = f2bf(v.w);
    ((ushort4_t*)out)[i] = r;
  }
}

// ---------- fused QKV projection GEMM ----------
__global__ __launch_bounds__(256, 2) void proj_gemm(
    const unsigned short* __restrict__ Xq, const unsigned short* __restrict__ Xk,
    const unsigned short* __restrict__ Xv,
    const unsigned short* __restrict__ Wqb, const unsigned short* __restrict__ Wkb,
    const unsigned short* __restrict__ Wvb,
    const float* __restrict__ bq, const float* __restrict__ bk, const float* __restrict__ bv,
    unsigned short* __restrict__ QP, unsigned short* __restrict__ KP,
    unsigned short* __restrict__ VP) {
  const int tid = threadIdx.x;
  const int wid = tid >> 6, lane = tid & 63;
  const int l16 = lane & 15, hi = lane >> 4;
  const int m0 = blockIdx.x * 128;
  const int sel = blockIdx.y >> 3;
  const int n0 = (blockIdx.y & 7) * 128;

  const unsigned short* X; const unsigned short* W; const float* bias; unsigned short* out;
  if (sel == 0)      { X = Xq; W = Wqb; bias = bq; out = QP; }
  else if (sel == 1) { X = Xk; W = Wkb; bias = bk; out = KP; }
  else               { X = Xv; W = Wvb; bias = bv; out = VP; }

  __shared__ unsigned short stage[2 * 128 * 32];

  f32x4 acc[4][4] = {};
  const int wm = (wid >> 1) * 64, wn = (wid & 1) * 64;

  for (int kt = 0; kt < 1024; kt += 32) {
#pragma unroll
    for (int t = 0; t < 4; ++t) {
      int g = wid * 4 + t;
      int c = g & 7;
      int row = c * 16 + (lane >> 2);
      int ko = (lane & 3) * 8;
      const unsigned short* src = (g < 8)
          ? (X + (size_t)(m0 + row) * 1024 + kt + ko)
          : (W + (size_t)(n0 + row) * 1024 + kt + ko);
      gload_lds16(src, (unsigned short*)((char*)stage + g * 1024));
    }
    __syncthreads();

    short8 af[4], bfr[4];
#pragma unroll
    for (int i = 0; i < 4; ++i)
      af[i] = ld_s8(&stage[(wm + i * 16 + l16) * 32 + hi * 8]);
#pragma unroll
    for (int j = 0; j < 4; ++j)
      bfr[j] = ld_s8(&stage[4096 + (wn + j * 16 + l16) * 32 + hi * 8]);
#pragma unroll
    for (int i = 0; i < 4; ++i)
#pragma unroll
      for (int j = 0; j < 4; ++j)
        acc[i][j] = __builtin_amdgcn_mfma_f32_16x16x32_bf16(af[i], bfr[j], acc[i][j], 0, 0, 0);
    __syncthreads();
  }

#pragma unroll
  for (int j = 0; j < 4; ++j) {
    int feat = n0 + wn + j * 16 + l16;
    float bi = bias[feat];
    int h = feat >> 6, d = feat & 63;
#pragma unroll
    for (int i = 0; i < 4; ++i) {
#pragma unroll
      for (int r = 0; r < 4; ++r) {
        int m = m0 + wm + i * 16 + hi * 4 + r;
        int b = m >> 11, n = m & 2047;
        float v = acc[i][j][r] + bi;
        out[(((size_t)(b * 16 + h)) * 2048 + n) * 64 + d] = f2bf(v);
      }
    }
  }
}

// ---------- flash attention ----------
#define PSTR 88
__global__ __launch_bounds__(256, 2) void attn_kernel(
    const unsigned short* __restrict__ Q, const unsigned short* __restrict__ K,
    const unsigned short* __restrict__ V,
    const float* __restrict__ weights,
    const unsigned char* __restrict__ mask8, const int* __restrict__ mask32,
    const float* __restrict__ maskf, const int* __restrict__ mfmt,
    unsigned short* __restrict__ O) {
  const int qt = blockIdx.x, bh = blockIdx.y;
  const int b = bh >> 4, h = bh & 15;
  const int tid = threadIdx.x, wid = tid >> 6, lane = tid & 63;
  const int l16 = lane & 15, hi = lane >> 4;
  const size_t bh_nd = (size_t)bh * 2048 * 64;
  const size_t bh_nn = (size_t)bh * 2048 * 2048;
  const int q0 = qt * 64;
  const int qrow_frag = q0 + wid * 16 + l16;
  const int qrow_d = q0 + wid * 16 + hi * 4;
  const int fmt = *mfmt;

  short8 qf[2];
  qf[0] = ld_g8(Q + bh_nd + (size_t)qrow_frag * 64 + hi * 8);
  qf[1] = ld_g8(Q + bh_nd + (size_t)qrow_frag * 64 + 32 + hi * 8);

  __shared__ unsigned short vT[64 * PSTR];
  __shared__ unsigned short plds[4][16 * PSTR];

  f32x4 o[4] = {};
  float mrow[4], lrow[4];
#pragma unroll
  for (int r = 0; r < 4; ++r) { mrow[r] = -1e30f; lrow[r] = 0.f; }

  for (int kt0 = 0; kt0 < 2048; kt0 += 64) {
#pragma unroll
    for (int it = 0; it < 2; ++it) {
      int c = tid + it * 256;
      int row = c >> 3, ds = (c & 7) * 8;
      short8 v = ld_g8(V + bh_nd + (size_t)(kt0 + row) * 64 + ds);
#pragma unroll
      for (int e = 0; e < 8; ++e) vT[(ds + e) * PSTR + row] = (unsigned short)v[e];
    }
    __syncthreads();

    f32x4 s[4];
#pragma unroll
    for (int c0 = 0; c0 < 4; ++c0) {
      f32x4 z = {};
#pragma unroll
      for (int kh = 0; kh < 2; ++kh) {
        short8 kf = ld_g8(K + bh_nd + (size_t)(kt0 + c0 * 16 + l16) * 64 + kh * 32 + hi * 8);
        z = __builtin_amdgcn_mfma_f32_16x16x32_bf16(qf[kh], kf, z, 0, 0, 0);
      }
      s[c0] = z;
    }

#pragma unroll
    for (int c0 = 0; c0 < 4; ++c0) {
#pragma unroll
      for (int r = 0; r < 4; ++r) {
        int row = qrow_d + r;
        int col = kt0 + c0 * 16 + l16;
        size_t idx = bh_nn + (size_t)row * 2048 + col;
        float w = weights[idx];
        bool mk;
        if (fmt == 1)      mk = mask32[idx] != 0;
        else if (fmt == 0) mk = mask8[idx] != 0;
        else               mk = maskf[idx] != 0.0f;
        s[c0][r] = mk ? -INFINITY : s[c0][r] * 0.125f * w;
      }
    }

    float tmax[4];
#pragma unroll
    for (int r = 0; r < 4; ++r)
      tmax[r] = fmaxf(fmaxf(s[0][r], s[1][r]), fmaxf(s[2][r], s[3][r]));
#pragma unroll
    for (int msk = 1; msk < 16; msk <<= 1)
#pragma unroll
      for (int r = 0; r < 4; ++r) tmax[r] = fmaxf(tmax[r], __shfl_xor(tmax[r], msk));
#pragma unroll
    for (int r = 0; r < 4; ++r) {
      float mnew = fmaxf(mrow[r], tmax[r]);
      float sc = __expf(mrow[r] - mnew);
      mrow[r] = mnew; lrow[r] *= sc;
#pragma unroll
      for (int d0 = 0; d0 < 4; ++d0) o[d0][r] *= sc;
    }
    float psum[4];
#pragma unroll
    for (int r = 0; r < 4; ++r) {
#pragma unroll
      for (int c0 = 0; c0 < 4; ++c0) s[c0][r] = __expf(s[c0][r] - mrow[r]);
      psum[r] = s[0][r] + s[1][r] + s[2][r] + s[3][r];
    }
#pragma unroll
    for (int msk = 1; msk < 16; msk <<= 1)
#pragma unroll
      for (int r = 0; r < 4; ++r) psum[r] += __shfl_xor(psum[r], msk);
#pragma unroll
    for (int r = 0; r < 4; ++r) lrow[r] += psum[r];

#pragma unroll
    for (int c0 = 0; c0 < 4; ++c0)
#pragma unroll
      for (int r = 0; r < 4; ++r)
        plds[wid][(hi * 4 + r) * PSTR + c0 * 16 + l16] = f2bf(s[c0][r]);

    short8 pa[2];
    pa[0] = ld_s8(&plds[wid][l16 * PSTR + hi * 8]);
    pa[1] = ld_s8(&plds[wid][l16 * PSTR + 32 + hi * 8]);
#pragma unroll
    for (int d0 = 0; d0 < 4; ++d0) {
#pragma unroll
      for (int kh = 0; kh < 2; ++kh) {
        short8 vb = ld_s8(&vT[(d0 * 16 + l16) * PSTR + kh * 32 + hi * 8]);
        o[d0] = __builtin_amdgcn_mfma_f32_16x16x32_bf16(pa[kh], vb, o[d0], 0, 0, 0);
      }
    }
    __syncthreads();
  }

#pragma unroll
  for (int r = 0; r < 4; ++r) {
    float inv = 1.0f / lrow[r];
    int row = qrow_d + r;
#pragma unroll
    for (int d0 = 0; d0 < 4; ++d0)
      O[((size_t)(b * 2048 + row)) * 1024 + h * 64 + d0 * 16 + l16] = f2bf(o[d0][r] * inv);
  }
}

// ---------- output projection GEMM (fp32 out) ----------
__global__ __launch_bounds__(256, 2) void out_gemm(
    const unsigned short* __restrict__ A, const unsigned short* __restrict__ W,
    const float* __restrict__ bias, float* __restrict__ Cout) {
  const int tid = threadIdx.x;
  const int wid = tid >> 6, lane = tid & 63;
  const int l16 = lane & 15, hi = lane >> 4;
  const int m0 = blockIdx.x * 128;
  const int n0 = blockIdx.y * 128;

  __shared__ unsigned short stage[2 * 128 * 32];
  f32x4 acc[4][4] = {};
  const int wm = (wid >> 1) * 64, wn = (wid & 1) * 64;

  for (int kt = 0; kt < 1024; kt += 32) {
#pragma unroll
    for (int t = 0; t < 4; ++t) {
      int g = wid * 4 + t;
      int c = g & 7;
      int row = c * 16 + (lane >> 2);
      int ko = (lane & 3) * 8;
      const unsigned short* src = (g < 8)
          ? (A + (size_t)(m0 + row) * 1024 + kt + ko)
          : (W + (size_t)(n0 + row) * 1024 + kt + ko);
      gload_lds16(src, (unsigned short*)((char*)stage + g * 1024));
    }
    __syncthreads();

    short8 af[4], bfr[4];
#pragma unroll
    for (int i = 0; i < 4; ++i)
      af[i] = ld_s8(&stage[(wm + i * 16 + l16) * 32 + hi * 8]);
#pragma unroll
    for (int j = 0; j < 4; ++j)
      bfr[j] = ld_s8(&stage[4096 + (wn + j * 16 + l16) * 32 + hi * 8]);
#pragma unroll
    for (int i = 0; i < 4; ++i)
#pragma unroll
      for (int j = 0; j < 4; ++j)
        acc[i][j] = __builtin_amdgcn_mfma_f32_16x16x32_bf16(af[i], bfr[j], acc[i][j], 0, 0, 0);
    __syncthreads();
  }

#pragma unroll
  for (int j = 0; j < 4; ++j) {
    int feat = n0 + wn + j * 16 + l16;
    float bi = bias[feat];
#pragma unroll
    for (int i = 0; i < 4; ++i) {
#pragma unroll
      for (int r = 0; r < 4; ++r) {
        int m = m0 + wm + i * 16 + hi * 4 + r;
        Cout[(size_t)m * 1024 + feat] = acc[i][j][r] + bi;
      }
    }
  }
}

// ---------- launch ----------
extern "C" void kernel_launch(void* const* d_in, const int* in_sizes, int n_in,
                              void* d_out, int out_size, void* d_ws, size_t ws_size,
                              hipStream_t stream) {
  const float* queries = (const float*)d_in[0];
  const float* keys    = (const float*)d_in[1];
  const float* values  = (const float*)d_in[2];
  const void*  maskp   = d_in[3];
  const float* weights = (const float*)d_in[4];
  const float* Wq = (const float*)d_in[5];
  const float* bq = (const float*)d_in[6];
  const float* Wk = (const float*)d_in[7];
  const float* bk = (const float*)d_in[8];
  const float* Wv = (const float*)d_in[9];
  const float* bv = (const float*)d_in[10];
  const float* Wo = (const float*)d_in[11];
  const float* bo = (const float*)d_in[12];

  unsigned short* ws = (unsigned short*)d_ws;
  unsigned short* Xq  = ws;                 // 4194304 each; OB aliases Xq after proj
  unsigned short* Xk  = ws + 4194304;
  unsigned short* Xv  = ws + 8388608;
  unsigned short* Wqb = ws + 12582912;      // 1048576 each
  unsigned short* Wkb = ws + 13631488;
  unsigned short* Wvb = ws + 14680064;
  unsigned short* Wob = ws + 15728640;
  unsigned short* QP  = ws + 16777216;      // (b,h,n,d) 4194304 each
  unsigned short* KP  = ws + 20971520;
  unsigned short* VP  = ws + 25165824;
  unsigned short* OB  = Xq;                 // reuse (dead after proj_gemm)
  int* mflag = (int*)(ws + 29360128);       // 56 MiB offset, within prior footprint

  detect_mask_fmt<<<1, 64, 0, stream>>>((const unsigned int*)maskp, mflag);

  cvt_kernel<<<4096, 256, 0, stream>>>(queries, Xq, 1048576);
  cvt_kernel<<<4096, 256, 0, stream>>>(keys,    Xk, 1048576);
  cvt_kernel<<<4096, 256, 0, stream>>>(values,  Xv, 1048576);
  cvt_kernel<<<1024, 256, 0, stream>>>(Wq, Wqb, 262144);
  cvt_kernel<<<1024, 256, 0, stream>>>(Wk, Wkb, 262144);
  cvt_kernel<<<1024, 256, 0, stream>>>(Wv, Wvb, 262144);
  cvt_kernel<<<1024, 256, 0, stream>>>(Wo, Wob, 262144);

  proj_gemm<<<dim3(32, 24), 256, 0, stream>>>(Xq, Xk, Xv, Wqb, Wkb, Wvb,
                                              bq, bk, bv, QP, KP, VP);
  attn_kernel<<<dim3(32, 32), 256, 0, stream>>>(
      QP, KP, VP, weights,
      (const unsigned char*)maskp, (const int*)maskp, (const float*)maskp, mflag, OB);
  out_gemm<<<dim3(32, 8), 256, 0, stream>>>(OB, Wob, bo, (float*)d_out);
}

// Round 3
// 532.388 us; speedup vs baseline: 1.1093x; 1.1093x over previous
//
#include <hip/hip_runtime.h>
#include <stdint.h>

#define DEV __device__ __forceinline__

typedef __attribute__((__ext_vector_type__(8))) short short8;
typedef __attribute__((__ext_vector_type__(4))) float f32x4;
typedef __attribute__((__ext_vector_type__(4))) unsigned short ushort4_t;

// ---------- helpers ----------
DEV unsigned short f2bf(float f) {
  union { float f; unsigned u; } x; x.f = f;
  unsigned u = x.u;
  unsigned r = (u + 0x7FFFu + ((u >> 16) & 1u)) >> 16;  // RNE
  return (unsigned short)r;
}

DEV void gload_lds16(const void* g, void* l) {
  __builtin_amdgcn_global_load_lds(
      (const __attribute__((address_space(1))) unsigned int*)g,
      (__attribute__((address_space(3))) unsigned int*)l,
      16, 0, 0);
}

DEV short8 ld_g8(const unsigned short* p) { return *(const short8*)p; }
DEV short8 ld_s8(const unsigned short* p) { return *(const short8*)p; }

// ---------- mask dtype detection ----------
// fmt: 0 = packed bool bytes, 1 = int32 0/1, 2 = float32 0.0/1.0
__global__ void detect_mask_fmt(const unsigned int* __restrict__ mask, int* __restrict__ flag) {
  if (threadIdx.x == 0 && blockIdx.x == 0) {
    int fmt = 1;
    for (int i = 0; i < 256; ++i) {
      unsigned u = mask[i];
      if (u == 0x3F800000u) { fmt = 2; break; }
      if ((u & 0xFFFFFF00u) != 0u) { fmt = 0; break; }
    }
    *flag = fmt;
  }
}

// ---------- fused fp32 -> bf16 convert (all 7 tensors, one launch) ----------
__global__ void cvt_all(const float* __restrict__ q, const float* __restrict__ k,
                        const float* __restrict__ v,
                        const float* __restrict__ wq, const float* __restrict__ wk,
                        const float* __restrict__ wv, const float* __restrict__ wo,
                        unsigned short* __restrict__ Xq, unsigned short* __restrict__ Xk,
                        unsigned short* __restrict__ Xv, unsigned short* __restrict__ Wqb,
                        unsigned short* __restrict__ Wkb, unsigned short* __restrict__ Wvb,
                        unsigned short* __restrict__ Wob) {
  int i = blockIdx.x * 256 + threadIdx.x;
  const float* src; unsigned short* dst; int off;
  if (i < 1048576)      { src = q;  dst = Xq;  off = i; }
  else if (i < 2097152) { src = k;  dst = Xk;  off = i - 1048576; }
  else if (i < 3145728) { src = v;  dst = Xv;  off = i - 2097152; }
  else if (i < 3407872) { src = wq; dst = Wqb; off = i - 3145728; }
  else if (i < 3670016) { src = wk; dst = Wkb; off = i - 3407872; }
  else if (i < 3932160) { src = wv; dst = Wvb; off = i - 3670016; }
  else                  { src = wo; dst = Wob; off = i - 3932160; }
  float4 vv = ((const float4*)src)[off];
  ushort4_t r;
  r.x = f2bf(vv.x); r.y = f2bf(vv.y); r.z = f2bf(vv.z); r.w = f2bf(vv.w);
  ((ushort4_t*)dst)[off] = r;
}

// ---------- fused QKV projection GEMM ----------
__global__ __launch_bounds__(256, 2) void proj_gemm(
    const unsigned short* __restrict__ Xq, const unsigned short* __restrict__ Xk,
    const unsigned short* __restrict__ Xv,
    const unsigned short* __restrict__ Wqb, const unsigned short* __restrict__ Wkb,
    const unsigned short* __restrict__ Wvb,
    const float* __restrict__ bq, const float* __restrict__ bk, const float* __restrict__ bv,
    unsigned short* __restrict__ QP, unsigned short* __restrict__ KP,
    unsigned short* __restrict__ VP) {
  const int tid = threadIdx.x;
  const int wid = tid >> 6, lane = tid & 63;
  const int l16 = lane & 15, hi = lane >> 4;
  const int m0 = blockIdx.x * 128;
  const int sel = blockIdx.y >> 3;
  const int n0 = (blockIdx.y & 7) * 128;

  const unsigned short* X; const unsigned short* W; const float* bias; unsigned short* out;
  if (sel == 0)      { X = Xq; W = Wqb; bias = bq; out = QP; }
  else if (sel == 1) { X = Xk; W = Wkb; bias = bk; out = KP; }
  else               { X = Xv; W = Wvb; bias = bv; out = VP; }

  __shared__ unsigned short stage[2 * 128 * 32];

  f32x4 acc[4][4] = {};
  const int wm = (wid >> 1) * 64, wn = (wid & 1) * 64;

  for (int kt = 0; kt < 1024; kt += 32) {
#pragma unroll
    for (int t = 0; t < 4; ++t) {
      int g = wid * 4 + t;
      int c = g & 7;
      int row = c * 16 + (lane >> 2);
      int ko = (lane & 3) * 8;
      const unsigned short* src = (g < 8)
          ? (X + (size_t)(m0 + row) * 1024 + kt + ko)
          : (W + (size_t)(n0 + row) * 1024 + kt + ko);
      gload_lds16(src, (unsigned short*)((char*)stage + g * 1024));
    }
    __syncthreads();

    short8 af[4], bfr[4];
#pragma unroll
    for (int i = 0; i < 4; ++i)
      af[i] = ld_s8(&stage[(wm + i * 16 + l16) * 32 + hi * 8]);
#pragma unroll
    for (int j = 0; j < 4; ++j)
      bfr[j] = ld_s8(&stage[4096 + (wn + j * 16 + l16) * 32 + hi * 8]);
#pragma unroll
    for (int i = 0; i < 4; ++i)
#pragma unroll
      for (int j = 0; j < 4; ++j)
        acc[i][j] = __builtin_amdgcn_mfma_f32_16x16x32_bf16(af[i], bfr[j], acc[i][j], 0, 0, 0);
    __syncthreads();
  }

#pragma unroll
  for (int j = 0; j < 4; ++j) {
    int feat = n0 + wn + j * 16 + l16;
    float bi = bias[feat];
    int h = feat >> 6, d = feat & 63;
#pragma unroll
    for (int i = 0; i < 4; ++i) {
#pragma unroll
      for (int r = 0; r < 4; ++r) {
        int m = m0 + wm + i * 16 + hi * 4 + r;
        int b = m >> 11, n = m & 2047;
        float v = acc[i][j][r] + bi;
        out[(((size_t)(b * 16 + h)) * 2048 + n) * 64 + d] = f2bf(v);
      }
    }
  }
}

// ---------- flash attention (reg-staged weights/mask/V pipeline) ----------
#define VSTR 72
#define WSTR 68
__global__ __launch_bounds__(256, 3) void attn_kernel(
    const unsigned short* __restrict__ Q, const unsigned short* __restrict__ K,
    const unsigned short* __restrict__ V,
    const float* __restrict__ weights,
    const unsigned char* __restrict__ mask8, const unsigned int* __restrict__ mask32,
    const int* __restrict__ mfmt,
    unsigned short* __restrict__ O) {
  // XCD-aware remap: all 32 q-tiles of one bh on one XCD (bid%8 constant per bh)
  const int bid = blockIdx.x;
  const int r8 = bid & 7, g = bid >> 3;
  const int qt = g & 31, bh = r8 + 8 * (g >> 5);
  const int b = bh >> 4, h = bh & 15;
  const int tid = threadIdx.x, wid = tid >> 6, lane = tid & 63;
  const int l16 = lane & 15, hi = lane >> 4;
  const size_t bh_nd = (size_t)bh * 2048 * 64;
  const size_t bh_nn = (size_t)bh * 2048 * 2048;
  const int q0 = qt * 64;
  const int qrow_frag = q0 + wid * 16 + l16;
  const int qrow_d = q0 + wid * 16 + hi * 4;
  const int fmt = *mfmt;
  const bool m4 = (fmt != 0);

  short8 qf[2];
  qf[0] = ld_g8(Q + bh_nd + (size_t)qrow_frag * 64 + hi * 8);
  qf[1] = ld_g8(Q + bh_nd + (size_t)qrow_frag * 64 + 32 + hi * 8);

  __shared__ unsigned short vT[64 * VSTR];        // vT[d][kk]
  __shared__ unsigned short plds[4][16 * VSTR];   // per-wave P tile
  __shared__ float wlds[64 * WSTR];               // weights tile [qrow][kk]
  __shared__ unsigned int mlds[64 * WSTR];        // mask words   [qrow][kk]

  // prefetch geometry: thread covers w/m tile row prow, cols pcol..pcol+15,
  // and V tile k-row vk, d cols vdb..vdb+15
  const int prow = tid >> 2, pcol = (tid & 3) << 4;
  const int vk = tid >> 2, vdb = (tid & 3) << 4;
  const float* wbase = weights + bh_nn + (size_t)(q0 + prow) * 2048 + pcol;
  const unsigned int* m32b = mask32 + bh_nn + (size_t)(q0 + prow) * 2048 + pcol;
  const unsigned char* m8b = mask8 + bh_nn + (size_t)(q0 + prow) * 2048 + pcol;
  const unsigned short* vbase = V + bh_nd + (size_t)vk * 64 + vdb;

  uint4 wreg[4], mreg[4];
  short8 vreg[2];

#define PF(kt)                                                           \
  {                                                                      \
    _Pragma("unroll")                                                    \
    for (int j = 0; j < 4; ++j)                                          \
      wreg[j] = *(const uint4*)(wbase + (kt) + j * 4);                   \
    if (m4) {                                                            \
      _Pragma("unroll")                                                  \
      for (int j = 0; j < 4; ++j)                                        \
        mreg[j] = *(const uint4*)(m32b + (kt) + j * 4);                  \
    } else {                                                             \
      mreg[0] = *(const uint4*)(m8b + (kt));                             \
    }                                                                    \
    vreg[0] = ld_g8(vbase + (size_t)(kt) * 64);                          \
    vreg[1] = ld_g8(vbase + (size_t)(kt) * 64 + 8);                      \
  }

  f32x4 o[4] = {};
  float mrow[4], lrow[4];
#pragma unroll
  for (int r = 0; r < 4; ++r) { mrow[r] = -1e30f; lrow[r] = 0.f; }

  PF(0);

  for (int t = 0; t < 32; ++t) {
    const int kt0 = t * 64;

    // ---- dump staged regs to LDS (compiler inserts vmcnt waits) ----
#pragma unroll
    for (int j = 0; j < 4; ++j)
      *(uint4*)&wlds[prow * WSTR + pcol + j * 4] = wreg[j];
    if (m4) {
#pragma unroll
      for (int j = 0; j < 4; ++j)
        *(uint4*)&mlds[prow * WSTR + pcol + j * 4] = mreg[j];
    } else {
      unsigned int wv[4] = {mreg[0].x, mreg[0].y, mreg[0].z, mreg[0].w};
#pragma unroll
      for (int j = 0; j < 4; ++j)
#pragma unroll
        for (int e = 0; e < 4; ++e)
          mlds[prow * WSTR + pcol + j * 4 + e] = (wv[j] >> (8 * e)) & 0xFFu;
    }
#pragma unroll
    for (int c = 0; c < 2; ++c)
#pragma unroll
      for (int e = 0; e < 8; ++e)
        vT[(vdb + c * 8 + e) * VSTR + vk] = (unsigned short)vreg[c][e];
    __syncthreads();

    // ---- K fragments FIRST (so their vmcnt wait doesn't drain prefetch) ----
    short8 kf[4][2];
#pragma unroll
    for (int c0 = 0; c0 < 4; ++c0)
#pragma unroll
      for (int kh = 0; kh < 2; ++kh)
        kf[c0][kh] = ld_g8(K + bh_nd + (size_t)(kt0 + c0 * 16 + l16) * 64 + kh * 32 + hi * 8);

    // ---- issue next tile's prefetch (stays in flight under compute) ----
    if (t < 31) PF(kt0 + 64);

    // ---- QK^T ----
    f32x4 s[4];
#pragma unroll
    for (int c0 = 0; c0 < 4; ++c0) {
      f32x4 z = {};
      z = __builtin_amdgcn_mfma_f32_16x16x32_bf16(qf[0], kf[c0][0], z, 0, 0, 0);
      z = __builtin_amdgcn_mfma_f32_16x16x32_bf16(qf[1], kf[c0][1], z, 0, 0, 0);
      s[c0] = z;
    }

    // ---- scale*weights, mask -> -inf (branchless, from LDS) ----
#pragma unroll
    for (int c0 = 0; c0 < 4; ++c0) {
#pragma unroll
      for (int r = 0; r < 4; ++r) {
        int li = (wid * 16 + hi * 4 + r) * WSTR + c0 * 16 + l16;
        float w = wlds[li];
        unsigned int mw = mlds[li];
        s[c0][r] = mw ? -INFINITY : s[c0][r] * 0.125f * w;
      }
    }

    // ---- online softmax ----
    float tmax[4];
#pragma unroll
    for (int r = 0; r < 4; ++r)
      tmax[r] = fmaxf(fmaxf(s[0][r], s[1][r]), fmaxf(s[2][r], s[3][r]));
#pragma unroll
    for (int msk = 1; msk < 16; msk <<= 1)
#pragma unroll
      for (int r = 0; r < 4; ++r) tmax[r] = fmaxf(tmax[r], __shfl_xor(tmax[r], msk));
#pragma unroll
    for (int r = 0; r < 4; ++r) {
      float mnew = fmaxf(mrow[r], tmax[r]);
      float sc = __expf(mrow[r] - mnew);
      mrow[r] = mnew; lrow[r] *= sc;
#pragma unroll
      for (int d0 = 0; d0 < 4; ++d0) o[d0][r] *= sc;
    }
    float psum[4];
#pragma unroll
    for (int r = 0; r < 4; ++r) {
#pragma unroll
      for (int c0 = 0; c0 < 4; ++c0) s[c0][r] = __expf(s[c0][r] - mrow[r]);
      psum[r] = s[0][r] + s[1][r] + s[2][r] + s[3][r];
    }
#pragma unroll
    for (int msk = 1; msk < 16; msk <<= 1)
#pragma unroll
      for (int r = 0; r < 4; ++r) psum[r] += __shfl_xor(psum[r], msk);
#pragma unroll
    for (int r = 0; r < 4; ++r) lrow[r] += psum[r];

    // ---- P -> per-wave LDS (layout change D->A), then PV ----
#pragma unroll
    for (int c0 = 0; c0 < 4; ++c0)
#pragma unroll
      for (int r = 0; r < 4; ++r)
        plds[wid][(hi * 4 + r) * VSTR + c0 * 16 + l16] = f2bf(s[c0][r]);

    short8 pa[2];
    pa[0] = ld_s8(&plds[wid][l16 * VSTR + hi * 8]);
    pa[1] = ld_s8(&plds[wid][l16 * VSTR + 32 + hi * 8]);
#pragma unroll
    for (int d0 = 0; d0 < 4; ++d0) {
#pragma unroll
      for (int kh = 0; kh < 2; ++kh) {
        short8 vb = ld_s8(&vT[(d0 * 16 + l16) * VSTR + kh * 32 + hi * 8]);
        o[d0] = __builtin_amdgcn_mfma_f32_16x16x32_bf16(pa[kh], vb, o[d0], 0, 0, 0);
      }
    }
    __syncthreads();
  }

  // ---- epilogue ----
#pragma unroll
  for (int r = 0; r < 4; ++r) {
    float inv = 1.0f / lrow[r];
    int row = qrow_d + r;
#pragma unroll
    for (int d0 = 0; d0 < 4; ++d0)
      O[((size_t)(b * 2048 + row)) * 1024 + h * 64 + d0 * 16 + l16] = f2bf(o[d0][r] * inv);
  }
#undef PF
}

// ---------- output projection GEMM (fp32 out) ----------
__global__ __launch_bounds__(256, 2) void out_gemm(
    const unsigned short* __restrict__ A, const unsigned short* __restrict__ W,
    const float* __restrict__ bias, float* __restrict__ Cout) {
  const int tid = threadIdx.x;
  const int wid = tid >> 6, lane = tid & 63;
  const int l16 = lane & 15, hi = lane >> 4;
  const int m0 = blockIdx.x * 128;
  const int n0 = blockIdx.y * 128;

  __shared__ unsigned short stage[2 * 128 * 32];
  f32x4 acc[4][4] = {};
  const int wm = (wid >> 1) * 64, wn = (wid & 1) * 64;

  for (int kt = 0; kt < 1024; kt += 32) {
#pragma unroll
    for (int t = 0; t < 4; ++t) {
      int g = wid * 4 + t;
      int c = g & 7;
      int row = c * 16 + (lane >> 2);
      int ko = (lane & 3) * 8;
      const unsigned short* src = (g < 8)
          ? (A + (size_t)(m0 + row) * 1024 + kt + ko)
          : (W + (size_t)(n0 + row) * 1024 + kt + ko);
      gload_lds16(src, (unsigned short*)((char*)stage + g * 1024));
    }
    __syncthreads();

    short8 af[4], bfr[4];
#pragma unroll
    for (int i = 0; i < 4; ++i)
      af[i] = ld_s8(&stage[(wm + i * 16 + l16) * 32 + hi * 8]);
#pragma unroll
    for (int j = 0; j < 4; ++j)
      bfr[j] = ld_s8(&stage[4096 + (wn + j * 16 + l16) * 32 + hi * 8]);
#pragma unroll
    for (int i = 0; i < 4; ++i)
#pragma unroll
      for (int j = 0; j < 4; ++j)
        acc[i][j] = __builtin_amdgcn_mfma_f32_16x16x32_bf16(af[i], bfr[j], acc[i][j], 0, 0, 0);
    __syncthreads();
  }

#pragma unroll
  for (int j = 0; j < 4; ++j) {
    int feat = n0 + wn + j * 16 + l16;
    float bi = bias[feat];
#pragma unroll
    for (int i = 0; i < 4; ++i) {
#pragma unroll
      for (int r = 0; r < 4; ++r) {
        int m = m0 + wm + i * 16 + hi * 4 + r;
        Cout[(size_t)m * 1024 + feat] = acc[i][j][r] + bi;
      }
    }
  }
}

// ---------- launch ----------
extern "C" void kernel_launch(void* const* d_in, const int* in_sizes, int n_in,
                              void* d_out, int out_size, void* d_ws, size_t ws_size,
                              hipStream_t stream) {
  const float* queries = (const float*)d_in[0];
  const float* keys    = (const float*)d_in[1];
  const float* values  = (const float*)d_in[2];
  const void*  maskp   = d_in[3];
  const float* weights = (const float*)d_in[4];
  const float* Wq = (const float*)d_in[5];
  const float* bq = (const float*)d_in[6];
  const float* Wk = (const float*)d_in[7];
  const float* bk = (const float*)d_in[8];
  const float* Wv = (const float*)d_in[9];
  const float* bv = (const float*)d_in[10];
  const float* Wo = (const float*)d_in[11];
  const float* bo = (const float*)d_in[12];

  unsigned short* ws = (unsigned short*)d_ws;
  unsigned short* Xq  = ws;                 // 4194304 each; OB aliases Xq after proj
  unsigned short* Xk  = ws + 4194304;
  unsigned short* Xv  = ws + 8388608;
  unsigned short* Wqb = ws + 12582912;      // 1048576 each
  unsigned short* Wkb = ws + 13631488;
  unsigned short* Wvb = ws + 14680064;
  unsigned short* Wob = ws + 15728640;
  unsigned short* QP  = ws + 16777216;      // (b,h,n,d) 4194304 each
  unsigned short* KP  = ws + 20971520;
  unsigned short* VP  = ws + 25165824;
  unsigned short* OB  = Xq;                 // reuse (dead after proj_gemm)
  int* mflag = (int*)(ws + 29360128);

  detect_mask_fmt<<<1, 64, 0, stream>>>((const unsigned int*)maskp, mflag);

  cvt_all<<<16384, 256, 0, stream>>>(queries, keys, values, Wq, Wk, Wv, Wo,
                                     Xq, Xk, Xv, Wqb, Wkb, Wvb, Wob);

  proj_gemm<<<dim3(32, 24), 256, 0, stream>>>(Xq, Xk, Xv, Wqb, Wkb, Wvb,
                                              bq, bk, bv, QP, KP, VP);
  attn_kernel<<<1024, 256, 0, stream>>>(
      QP, KP, VP, weights,
      (const unsigned char*)maskp, (const unsigned int*)maskp, mflag, OB);
  out_gemm<<<dim3(32, 8), 256, 0, stream>>>(OB, Wob, bo, (float*)d_out);
}

// Round 4
// 377.095 us; speedup vs baseline: 1.5662x; 1.4118x over previous
//
#include <hip/hip_runtime.h>
#include <stdint.h>

#define DEV __device__ __forceinline__

typedef __attribute__((__ext_vector_type__(8))) short short8;
typedef __attribute__((__ext_vector_type__(4))) float f32x4;
typedef __attribute__((__ext_vector_type__(4))) unsigned short ushort4_t;

// ---------- helpers ----------
DEV unsigned short f2bf(float f) {
  union { float f; unsigned u; } x; x.f = f;
  unsigned u = x.u;
  unsigned r = (u + 0x7FFFu + ((u >> 16) & 1u)) >> 16;  // RNE
  return (unsigned short)r;
}

DEV void gload_lds16(const void* g, void* l) {
  __builtin_amdgcn_global_load_lds(
      (const __attribute__((address_space(1))) unsigned int*)g,
      (__attribute__((address_space(3))) unsigned int*)l,
      16, 0, 0);
}

DEV short8 ld_g8(const unsigned short* p) { return *(const short8*)p; }
DEV short8 ld_s8(const unsigned short* p) { return *(const short8*)p; }

// ---------- mask dtype detection ----------
// fmt: 0 = packed bool bytes, 1 = int32 0/1, 2 = float32 0.0/1.0 (nonzero-word test works for 1&2)
__global__ void detect_mask_fmt(const unsigned int* __restrict__ mask, int* __restrict__ flag) {
  if (threadIdx.x == 0 && blockIdx.x == 0) {
    int fmt = 1;
    for (int i = 0; i < 256; ++i) {
      unsigned u = mask[i];
      if (u == 0x3F800000u) { fmt = 2; break; }
      if ((u & 0xFFFFFF00u) != 0u) { fmt = 0; break; }
    }
    *flag = fmt;
  }
}

// ---------- fused fp32 -> bf16 convert (all 7 tensors, one launch) ----------
__global__ void cvt_all(const float* __restrict__ q, const float* __restrict__ k,
                        const float* __restrict__ v,
                        const float* __restrict__ wq, const float* __restrict__ wk,
                        const float* __restrict__ wv, const float* __restrict__ wo,
                        unsigned short* __restrict__ Xq, unsigned short* __restrict__ Xk,
                        unsigned short* __restrict__ Xv, unsigned short* __restrict__ Wqb,
                        unsigned short* __restrict__ Wkb, unsigned short* __restrict__ Wvb,
                        unsigned short* __restrict__ Wob) {
  int i = blockIdx.x * 256 + threadIdx.x;
  const float* src; unsigned short* dst; int off;
  if (i < 1048576)      { src = q;  dst = Xq;  off = i; }
  else if (i < 2097152) { src = k;  dst = Xk;  off = i - 1048576; }
  else if (i < 3145728) { src = v;  dst = Xv;  off = i - 2097152; }
  else if (i < 3407872) { src = wq; dst = Wqb; off = i - 3145728; }
  else if (i < 3670016) { src = wk; dst = Wkb; off = i - 3407872; }
  else if (i < 3932160) { src = wv; dst = Wvb; off = i - 3670016; }
  else                  { src = wo; dst = Wob; off = i - 3932160; }
  float4 vv = ((const float4*)src)[off];
  ushort4_t r;
  r.x = f2bf(vv.x); r.y = f2bf(vv.y); r.z = f2bf(vv.z); r.w = f2bf(vv.w);
  ((ushort4_t*)dst)[off] = r;
}

// ---------- fused QKV projection GEMM ----------
// sel 0/1 (Q,K): out[b,h,n,d].  sel 2 (V): computes D[feat][token] (swapped operands)
// and stores V^T as VP_T[bh][d][n] with coalesced writes.
__global__ __launch_bounds__(256, 2) void proj_gemm(
    const unsigned short* __restrict__ Xq, const unsigned short* __restrict__ Xk,
    const unsigned short* __restrict__ Xv,
    const unsigned short* __restrict__ Wqb, const unsigned short* __restrict__ Wkb,
    const unsigned short* __restrict__ Wvb,
    const float* __restrict__ bq, const float* __restrict__ bk, const float* __restrict__ bv,
    unsigned short* __restrict__ QP, unsigned short* __restrict__ KP,
    unsigned short* __restrict__ VT) {
  const int tid = threadIdx.x;
  const int wid = tid >> 6, lane = tid & 63;
  const int l16 = lane & 15, hi = lane >> 4;
  const int m0 = blockIdx.x * 128;
  const int sel = blockIdx.y >> 3;
  const int n0 = (blockIdx.y & 7) * 128;

  const unsigned short* X; const unsigned short* W; const float* bias; unsigned short* out;
  if (sel == 0)      { X = Xq; W = Wqb; bias = bq; out = QP; }
  else if (sel == 1) { X = Xk; W = Wkb; bias = bk; out = KP; }
  else               { X = Xv; W = Wvb; bias = bv; out = VT; }

  __shared__ unsigned short stage[2 * 128 * 32];  // X tile @0, W tile @4096

  f32x4 acc[4][4] = {};
  const int wm = (wid >> 1) * 64, wn = (wid & 1) * 64;
  const int aoff = (sel == 2) ? 4096 : 0;   // V: A-frag from W tile
  const int boff = 4096 - aoff;

  for (int kt = 0; kt < 1024; kt += 32) {
#pragma unroll
    for (int t = 0; t < 4; ++t) {
      int g = wid * 4 + t;
      int c = g & 7;
      int row = c * 16 + (lane >> 2);
      int ko = (lane & 3) * 8;
      const unsigned short* src = (g < 8)
          ? (X + (size_t)(m0 + row) * 1024 + kt + ko)
          : (W + (size_t)(n0 + row) * 1024 + kt + ko);
      gload_lds16(src, (unsigned short*)((char*)stage + g * 1024));
    }
    __syncthreads();

    short8 af[4], bfr[4];
#pragma unroll
    for (int i = 0; i < 4; ++i)
      af[i] = ld_s8(&stage[aoff + (wm + i * 16 + l16) * 32 + hi * 8]);
#pragma unroll
    for (int j = 0; j < 4; ++j)
      bfr[j] = ld_s8(&stage[boff + (wn + j * 16 + l16) * 32 + hi * 8]);
#pragma unroll
    for (int i = 0; i < 4; ++i)
#pragma unroll
      for (int j = 0; j < 4; ++j)
        acc[i][j] = __builtin_amdgcn_mfma_f32_16x16x32_bf16(af[i], bfr[j], acc[i][j], 0, 0, 0);
    __syncthreads();
  }

  if (sel != 2) {
    // D rows = tokens (m), cols = feats (n); store (b,h,n,d)
#pragma unroll
    for (int j = 0; j < 4; ++j) {
      int feat = n0 + wn + j * 16 + l16;
      float bi = bias[feat];
      int h = feat >> 6, d = feat & 63;
#pragma unroll
      for (int i = 0; i < 4; ++i) {
#pragma unroll
        for (int r = 0; r < 4; ++r) {
          int m = m0 + wm + i * 16 + hi * 4 + r;
          int b = m >> 11, n = m & 2047;
          float v = acc[i][j][r] + bi;
          out[(((size_t)(b * 16 + h)) * 2048 + n) * 64 + d] = f2bf(v);
        }
      }
    }
  } else {
    // D rows = feats, cols = tokens; store VP_T[bh][d][n], lanes over n (coalesced)
#pragma unroll
    for (int j = 0; j < 4; ++j) {
      int tc0 = m0 + wn + j * 16;               // 16-aligned token block
      int b = tc0 >> 11, n = tc0 & 2047;
#pragma unroll
      for (int i = 0; i < 4; ++i) {
#pragma unroll
        for (int r = 0; r < 4; ++r) {
          int feat = n0 + wm + i * 16 + hi * 4 + r;
          int h = feat >> 6, d = feat & 63;
          float v = acc[i][j][r] + bias[feat];
          out[((size_t)(b * 16 + h) * 64 + d) * 2048 + n + l16] = f2bf(v);
        }
      }
    }
  }
}

// ---------- flash attention ----------
// grid 1024 (XCD-swizzled), block 256 = 4 waves x 16 q-rows, KBLK=32.
// weights/mask: direct-to-register 1-tile-ahead prefetch (8 f32 + 1 packed mask bit-word).
// V: pre-transposed VP_T staged linearly via global_load_lds, double-buffered.
__global__ __launch_bounds__(256, 3) void attn_kernel(
    const unsigned short* __restrict__ Q, const unsigned short* __restrict__ K,
    const unsigned short* __restrict__ VT,
    const float* __restrict__ weights,
    const unsigned char* __restrict__ mask8, const unsigned int* __restrict__ mask32,
    const int* __restrict__ mfmt,
    unsigned short* __restrict__ O) {
  const int bid = blockIdx.x;
  const int r8 = bid & 7, g = bid >> 3;
  const int qt = g & 31, bh = r8 + 8 * (g >> 5);
  const int b = bh >> 4, h = bh & 15;
  const int tid = threadIdx.x, wid = tid >> 6, lane = tid & 63;
  const int l16 = lane & 15, hi = lane >> 4;
  const size_t bh_nd = (size_t)bh * 2048 * 64;
  const size_t bh_nn = (size_t)bh * 2048 * 2048;
  const int q0 = qt * 64;
  const int qrow_frag = q0 + wid * 16 + l16;
  const int qrow_d = q0 + wid * 16 + hi * 4;
  const int fmt = *mfmt;
  const bool m4 = (fmt != 0);

  short8 qf[2];
  qf[0] = ld_g8(Q + bh_nd + (size_t)qrow_frag * 64 + hi * 8);
  qf[1] = ld_g8(Q + bh_nd + (size_t)qrow_frag * 64 + 32 + hi * 8);

  __shared__ unsigned short vTd[2][64 * 32];     // [d][k] linear, double-buffered
  __shared__ unsigned short plds[4][16 * 40];    // per-wave P tile, stride 40

  // V gload geometry: wave wid stages chunk wid (16 d-rows); lane -> 16B piece
  const int vd = wid * 16 + (lane >> 2);
  const int vko = (lane & 3) * 8;
  const unsigned short* vsrc = VT + bh_nd + (size_t)vd * 2048 + vko;

  const size_t wm_base = bh_nn + (size_t)qrow_d * 2048 + l16;

  f32x4 o[4] = {};
  float mrow[4], lrow[4];
#pragma unroll
  for (int r = 0; r < 4; ++r) { mrow[r] = -1e30f; lrow[r] = 0.f; }

  float wA[8], wB[8];
  unsigned mbA = 0, mbB = 0;

#define LOADWM(WW, MB, T)                                                  \
  {                                                                        \
    unsigned _mb = 0;                                                      \
    if (m4) {                                                              \
      _Pragma("unroll") for (int c0 = 0; c0 < 2; ++c0)                     \
      _Pragma("unroll") for (int r = 0; r < 4; ++r) {                      \
        size_t idx = wm_base + (size_t)r * 2048 + (T) * 32 + c0 * 16;      \
        WW[c0 * 4 + r] = 0.125f * weights[idx];                            \
        _mb |= (mask32[idx] ? 1u : 0u) << (c0 * 4 + r);                    \
      }                                                                    \
    } else {                                                               \
      _Pragma("unroll") for (int c0 = 0; c0 < 2; ++c0)                     \
      _Pragma("unroll") for (int r = 0; r < 4; ++r) {                      \
        size_t idx = wm_base + (size_t)r * 2048 + (T) * 32 + c0 * 16;      \
        WW[c0 * 4 + r] = 0.125f * weights[idx];                            \
        _mb |= (mask8[idx] ? 1u : 0u) << (c0 * 4 + r);                     \
      }                                                                    \
    }                                                                      \
    MB = _mb;                                                              \
  }

#define STEP(T, CUR, NXT, WC, MBC, WN, MBN)                                \
  {                                                                        \
    const int kt0 = (T) * 32;                                              \
    if ((T) + 1 < 64)                                                      \
      gload_lds16(vsrc + (size_t)(kt0 + 32),                               \
                  (unsigned short*)((char*)vTd[NXT] + wid * 1024));        \
    /* K fragments + QK^T */                                               \
    f32x4 s[2];                                                            \
    _Pragma("unroll") for (int c0 = 0; c0 < 2; ++c0) {                     \
      f32x4 z = {};                                                        \
      short8 k0 = ld_g8(K + bh_nd + (size_t)(kt0 + c0 * 16 + l16) * 64 + hi * 8); \
      short8 k1 = ld_g8(K + bh_nd + (size_t)(kt0 + c0 * 16 + l16) * 64 + 32 + hi * 8); \
      z = __builtin_amdgcn_mfma_f32_16x16x32_bf16(qf[0], k0, z, 0, 0, 0);  \
      z = __builtin_amdgcn_mfma_f32_16x16x32_bf16(qf[1], k1, z, 0, 0, 0);  \
      s[c0] = z;                                                           \
    }                                                                      \
    if ((T) + 1 < 64) LOADWM(WN, MBN, (T) + 1)                             \
    /* apply weights + mask */                                             \
    _Pragma("unroll") for (int c0 = 0; c0 < 2; ++c0)                       \
    _Pragma("unroll") for (int r = 0; r < 4; ++r)                          \
      s[c0][r] = ((MBC >> (c0 * 4 + r)) & 1) ? -INFINITY                   \
                                             : s[c0][r] * WC[c0 * 4 + r];  \
    /* online softmax */                                                   \
    float tmax[4];                                                         \
    _Pragma("unroll") for (int r = 0; r < 4; ++r)                          \
      tmax[r] = fmaxf(s[0][r], s[1][r]);                                   \
    _Pragma("unroll") for (int msk = 1; msk < 16; msk <<= 1)               \
    _Pragma("unroll") for (int r = 0; r < 4; ++r)                          \
      tmax[r] = fmaxf(tmax[r], __shfl_xor(tmax[r], msk));                  \
    _Pragma("unroll") for (int r = 0; r < 4; ++r) {                        \
      float mnew = fmaxf(mrow[r], tmax[r]);                                \
      float sc = __expf(mrow[r] - mnew);                                   \
      mrow[r] = mnew; lrow[r] *= sc;                                       \
      _Pragma("unroll") for (int d0 = 0; d0 < 4; ++d0) o[d0][r] *= sc;     \
    }                                                                      \
    float psum[4];                                                         \
    _Pragma("unroll") for (int r = 0; r < 4; ++r) {                        \
      s[0][r] = __expf(s[0][r] - mrow[r]);                                 \
      s[1][r] = __expf(s[1][r] - mrow[r]);                                 \
      psum[r] = s[0][r] + s[1][r];                                         \
    }                                                                      \
    _Pragma("unroll") for (int msk = 1; msk < 16; msk <<= 1)               \
    _Pragma("unroll") for (int r = 0; r < 4; ++r)                          \
      psum[r] += __shfl_xor(psum[r], msk);                                 \
    _Pragma("unroll") for (int r = 0; r < 4; ++r) lrow[r] += psum[r];      \
    /* P -> plds (D->A layout), PV */                                      \
    _Pragma("unroll") for (int c0 = 0; c0 < 2; ++c0)                       \
    _Pragma("unroll") for (int r = 0; r < 4; ++r)                          \
      plds[wid][(hi * 4 + r) * 40 + c0 * 16 + l16] = f2bf(s[c0][r]);       \
    short8 pa = ld_s8(&plds[wid][l16 * 40 + hi * 8]);                      \
    _Pragma("unroll") for (int d0 = 0; d0 < 4; ++d0) {                     \
      short8 vb = ld_s8(&vTd[CUR][(d0 * 16 + l16) * 32 + hi * 8]);         \
      o[d0] = __builtin_amdgcn_mfma_f32_16x16x32_bf16(pa, vb, o[d0], 0, 0, 0); \
    }                                                                      \
    __syncthreads();                                                       \
  }

  // prologue: tile 0
  LOADWM(wA, mbA, 0)
  gload_lds16(vsrc, (unsigned short*)((char*)vTd[0] + wid * 1024));
  __syncthreads();

  for (int t = 0; t < 64; t += 2) {
    STEP(t,     0, 1, wA, mbA, wB, mbB)
    STEP(t + 1, 1, 0, wB, mbB, wA, mbA)
  }

  // epilogue
#pragma unroll
  for (int r = 0; r < 4; ++r) {
    float inv = 1.0f / lrow[r];
    int row = qrow_d + r;
#pragma unroll
    for (int d0 = 0; d0 < 4; ++d0)
      O[((size_t)(b * 2048 + row)) * 1024 + h * 64 + d0 * 16 + l16] = f2bf(o[d0][r] * inv);
  }
#undef STEP
#undef LOADWM
}

// ---------- output projection GEMM (fp32 out) ----------
__global__ __launch_bounds__(256, 2) void out_gemm(
    const unsigned short* __restrict__ A, const unsigned short* __restrict__ W,
    const float* __restrict__ bias, float* __restrict__ Cout) {
  const int tid = threadIdx.x;
  const int wid = tid >> 6, lane = tid & 63;
  const int l16 = lane & 15, hi = lane >> 4;
  const int m0 = blockIdx.x * 128;
  const int n0 = blockIdx.y * 128;

  __shared__ unsigned short stage[2 * 128 * 32];
  f32x4 acc[4][4] = {};
  const int wm = (wid >> 1) * 64, wn = (wid & 1) * 64;

  for (int kt = 0; kt < 1024; kt += 32) {
#pragma unroll
    for (int t = 0; t < 4; ++t) {
      int g = wid * 4 + t;
      int c = g & 7;
      int row = c * 16 + (lane >> 2);
      int ko = (lane & 3) * 8;
      const unsigned short* src = (g < 8)
          ? (A + (size_t)(m0 + row) * 1024 + kt + ko)
          : (W + (size_t)(n0 + row) * 1024 + kt + ko);
      gload_lds16(src, (unsigned short*)((char*)stage + g * 1024));
    }
    __syncthreads();

    short8 af[4], bfr[4];
#pragma unroll
    for (int i = 0; i < 4; ++i)
      af[i] = ld_s8(&stage[(wm + i * 16 + l16) * 32 + hi * 8]);
#pragma unroll
    for (int j = 0; j < 4; ++j)
      bfr[j] = ld_s8(&stage[4096 + (wn + j * 16 + l16) * 32 + hi * 8]);
#pragma unroll
    for (int i = 0; i < 4; ++i)
#pragma unroll
      for (int j = 0; j < 4; ++j)
        acc[i][j] = __builtin_amdgcn_mfma_f32_16x16x32_bf16(af[i], bfr[j], acc[i][j], 0, 0, 0);
    __syncthreads();
  }

#pragma unroll
  for (int j = 0; j < 4; ++j) {
    int feat = n0 + wn + j * 16 + l16;
    float bi = bias[feat];
#pragma unroll
    for (int i = 0; i < 4; ++i) {
#pragma unroll
      for (int r = 0; r < 4; ++r) {
        int m = m0 + wm + i * 16 + hi * 4 + r;
        Cout[(size_t)m * 1024 + feat] = acc[i][j][r] + bi;
      }
    }
  }
}

// ---------- launch ----------
extern "C" void kernel_launch(void* const* d_in, const int* in_sizes, int n_in,
                              void* d_out, int out_size, void* d_ws, size_t ws_size,
                              hipStream_t stream) {
  const float* queries = (const float*)d_in[0];
  const float* keys    = (const float*)d_in[1];
  const float* values  = (const float*)d_in[2];
  const void*  maskp   = d_in[3];
  const float* weights = (const float*)d_in[4];
  const float* Wq = (const float*)d_in[5];
  const float* bq = (const float*)d_in[6];
  const float* Wk = (const float*)d_in[7];
  const float* bk = (const float*)d_in[8];
  const float* Wv = (const float*)d_in[9];
  const float* bv = (const float*)d_in[10];
  const float* Wo = (const float*)d_in[11];
  const float* bo = (const float*)d_in[12];

  unsigned short* ws = (unsigned short*)d_ws;
  unsigned short* Xq  = ws;                 // 4194304 each; OB aliases Xq after proj
  unsigned short* Xk  = ws + 4194304;
  unsigned short* Xv  = ws + 8388608;
  unsigned short* Wqb = ws + 12582912;      // 1048576 each
  unsigned short* Wkb = ws + 13631488;
  unsigned short* Wvb = ws + 14680064;
  unsigned short* Wob = ws + 15728640;
  unsigned short* QP  = ws + 16777216;      // (b,h,n,d)
  unsigned short* KP  = ws + 20971520;      // (b,h,n,d)
  unsigned short* VPT = ws + 25165824;      // (b,h,d,n)  <- transposed
  unsigned short* OB  = Xq;                 // reuse (dead after proj_gemm)
  int* mflag = (int*)(ws + 29360128);

  detect_mask_fmt<<<1, 64, 0, stream>>>((const unsigned int*)maskp, mflag);

  cvt_all<<<16384, 256, 0, stream>>>(queries, keys, values, Wq, Wk, Wv, Wo,
                                     Xq, Xk, Xv, Wqb, Wkb, Wvb, Wob);

  proj_gemm<<<dim3(32, 24), 256, 0, stream>>>(Xq, Xk, Xv, Wqb, Wkb, Wvb,
                                              bq, bk, bv, QP, KP, VPT);
  attn_kernel<<<1024, 256, 0, stream>>>(
      QP, KP, VPT, weights,
      (const unsigned char*)maskp, (const unsigned int*)maskp, mflag, OB);
  out_gemm<<<dim3(32, 8), 256, 0, stream>>>(OB, Wob, bo, (float*)d_out);
}